// Round 12
// baseline (1572.082 us; speedup 1.0000x reference)
//
#include <hip/hip_runtime.h>
#include <hip/hip_bf16.h>

#define B_ 128
#define T_ 64
#define H_ 256
#define E_ 256
#define L_ 512
#define V_ 30522
#define EOS_ 2
#define BH_ (B_ * H_)

typedef __attribute__((ext_vector_type(8))) short bf16x8;
typedef __attribute__((ext_vector_type(4))) float f32x4;

__device__ __forceinline__ float4 ld4(const float* p) { return *(const float4*)p; }
__device__ __forceinline__ float dot4(float4 a, float4 b) {
  return a.x * b.x + a.y * b.y + a.z * b.z + a.w * b.w;
}
__device__ __forceinline__ float sigf(float x) {
  return __builtin_amdgcn_rcpf(1.f + __expf(-x));
}
__device__ __forceinline__ float tanh_fast(float x) {
  float e = __expf(2.f * x);
  return 1.f - 2.f * __builtin_amdgcn_rcpf(e + 1.f);
}
__device__ __forceinline__ f32x4 mfma16(bf16x8 a, bf16x8 b, f32x4 c) {
  return __builtin_amdgcn_mfma_f32_16x16x32_bf16(a, b, c, 0, 0, 0);
}

// ---------------------------------------------------------------------------
// generic f32 -> bf16 convert (total % 8 == 0)
// ---------------------------------------------------------------------------
__global__ __launch_bounds__(256) void conv_bf16(
    const float* __restrict__ src, __hip_bfloat16* __restrict__ dst, int total) {
  int i = (blockIdx.x * 256 + threadIdx.x) * 8;
  if (i + 8 <= total) {
    float4 lo = ld4(src + i), hi = ld4(src + i + 4);
    union { bf16x8 v8; __hip_bfloat16 e[8]; } u;
    u.e[0] = __float2bfloat16(lo.x); u.e[1] = __float2bfloat16(lo.y);
    u.e[2] = __float2bfloat16(lo.z); u.e[3] = __float2bfloat16(lo.w);
    u.e[4] = __float2bfloat16(hi.x); u.e[5] = __float2bfloat16(hi.y);
    u.e[6] = __float2bfloat16(hi.z); u.e[7] = __float2bfloat16(hi.w);
    *(bf16x8*)(dst + i) = u.v8;
  }
}

__global__ __launch_bounds__(256) void reset_cnt(int* __restrict__ c) {
  int i = blockIdx.x * 256 + threadIdx.x;
  if (i < 1056) c[i] = 0;
}

// ---------------------------------------------------------------------------
// init: h_init = z @ W_lat^T + b_lat -> slot 0 of h0 & hs (hi+res)
// ---------------------------------------------------------------------------
__global__ __launch_bounds__(256) void init_kernel(
    const float* __restrict__ z, const float* __restrict__ W_lat,
    const float* __restrict__ b_lat,
    __hip_bfloat16* __restrict__ h0hi, __hip_bfloat16* __restrict__ h0res,
    __hip_bfloat16* __restrict__ hshi, __hip_bfloat16* __restrict__ hsres) {
  int b = blockIdx.x;
  int h = threadIdx.x;
  const float* zr = z + (size_t)b * L_;
  const float* wr = W_lat + (size_t)h * L_;
  float acc = b_lat[h];
  #pragma unroll 4
  for (int l = 0; l < L_; l += 4) acc += dot4(ld4(zr + l), ld4(wr + l));
  __hip_bfloat16 hi = __float2bfloat16(acc);
  __hip_bfloat16 re = __float2bfloat16(acc - __bfloat162float(hi));
  int idx = b * H_ + h;
  h0hi[idx] = hi; h0res[idx] = re;
  hshi[idx] = hi; hsres[idx] = re;
}

// ---------------------------------------------------------------------------
// Persistent MFMA recurrence, XCD-pinned gang, PER-BLOCK MONOTONE FLAGS.
// R11 diagnosis: 16 producer RMWs on ONE counter address serialize at the
// IC (~6us/step); detection chained two such counters. Fix:
//  - flag0[i], flag1[i]: one int per producer block, 128B apart (distinct
//    IC lines) -> 16 signal RMWs proceed in parallel, fire-and-forget
//    (result discarded -> no-return global_atomic_add, no wave stall).
//  - consumers poll all 16(+16) flags IN PARALLEL: wave-0 lanes 0..15 poll
//    flag0, lanes 16..31 poll flag1, relaxed agent loads + __all ballot.
// Agent scope everywhere (R10 lesson: workgroup scope reads stale L1).
// No __threadfence: workers share XCD0's L2 (data coherence point); stores
// are drained to L2 by the vmcnt(0) in __syncthreads before signaling.
// Spin caps -> loud failure, never a hang. Flags zeroed each launch.
// ---------------------------------------------------------------------------
__device__ __forceinline__ void wait_flags(const int* f0, int need0,
                                           const int* f1, int need1) {
  if (threadIdx.x < 64) {
    const int lane = threadIdx.x;
    const int* p = nullptr;
    int need = 0;
    if (lane < 16) { p = f0 + lane * 32; need = need0; }
    else if (lane < 32 && f1 != nullptr) { p = f1 + (lane - 16) * 32; need = need1; }
    int it = 0;
    for (;;) {
      bool ok = true;
      if (p) ok = (__hip_atomic_load(p, __ATOMIC_RELAXED,
                                     __HIP_MEMORY_SCOPE_AGENT) >= need);
      if (__all(ok)) break;
      if (++it >= (1 << 15)) break;   // loud failure, not a hang
      __builtin_amdgcn_s_sleep(1);
    }
  }
  __syncthreads();   // exec+mem barrier: data loads cannot hoist above
}

__device__ __forceinline__ void signal_flag(int* f) {
  __syncthreads();               // all waves' stores vmcnt-drained -> in L2
  if (threadIdx.x == 0)
    __hip_atomic_fetch_add(f, 1, __ATOMIC_RELAXED, __HIP_MEMORY_SCOPE_AGENT);
}

__global__ __launch_bounds__(256, 1) void lstm_persist(
    const int* __restrict__ targ, const __hip_bfloat16* __restrict__ embB,
    const __hip_bfloat16* __restrict__ Wih0B, const __hip_bfloat16* __restrict__ Whh0B,
    const float* __restrict__ b_ih0, const float* __restrict__ b_hh0,
    const __hip_bfloat16* __restrict__ Wih1B, const __hip_bfloat16* __restrict__ Whh1B,
    const float* __restrict__ b_ih1, const float* __restrict__ b_hh1,
    __hip_bfloat16* __restrict__ h0hi, __hip_bfloat16* __restrict__ h0res,
    __hip_bfloat16* __restrict__ hshi, __hip_bfloat16* __restrict__ hsres,
    int* __restrict__ flag0, int* __restrict__ flag1, int* __restrict__ ticket) {
  // ---- XCD pinning: workers are the first 32 ticket-holders on XCD 0 ----
  __shared__ int role_sh;
  if (threadIdx.x == 0) {
    unsigned xcd;
    asm volatile("s_getreg_b32 %0, hwreg(HW_REG_XCC_ID)" : "=s"(xcd));
    int r = -1;
    if ((xcd & 7u) == 0u)
      r = __hip_atomic_fetch_add(ticket, 1, __ATOMIC_RELAXED,
                                 __HIP_MEMORY_SCOPE_AGENT);
    role_sh = r;
  }
  __syncthreads();
  const int blk = role_sh;
  if (blk < 0 || blk >= 32) return;

  const bool isL0 = blk < 16;
  const int chunk = isL0 ? blk : blk - 16;
  const int tid = threadIdx.x;
  const int lane = tid & 63;
  const int wave = tid >> 6;
  const int col = lane & 15;
  const int klo = lane >> 4;
  const int mbase = wave * 32;
  const int hcol = chunk * 16 + col;

  const float* bi = isL0 ? b_ih0 : b_ih1;
  const float* bh = isL0 ? b_hh0 : b_hh1;
  float bias[4];
  #pragma unroll
  for (int g = 0; g < 4; ++g) bias[g] = bi[g * 256 + hcol] + bh[g * 256 + hcol];

  // weight-stationary B-frags (L2-resident thereafter)
  const __hip_bfloat16* W1 = isL0 ? Wih0B : Wih1B;
  const __hip_bfloat16* W2 = isL0 ? Whh0B : Whh1B;
  bf16x8 bw1[4][8], bw2[4][8];
  #pragma unroll
  for (int g = 0; g < 4; ++g) {
    int row = g * 256 + hcol;
    #pragma unroll
    for (int ks = 0; ks < 8; ++ks) {
      bw1[g][ks] = *(const bf16x8*)(W1 + (size_t)row * 256 + ks * 32 + klo * 8);
      bw2[g][ks] = *(const bf16x8*)(W2 + (size_t)row * 256 + ks * 32 + klo * 8);
    }
  }

  const int b0 = mbase + col;
  const int b1 = mbase + 16 + col;
  f32x4 cst[2];
  cst[0] = (f32x4){0.f, 0.f, 0.f, 0.f};
  cst[1] = (f32x4){0.f, 0.f, 0.f, 0.f};

  for (int t = 0; t < T_; ++t) {
    if (isL0) {
      if (t) wait_flags(flag0, t, nullptr, 0);            // h0 slot t done
    } else {
      wait_flags(flag0, t + 1, t ? flag1 : nullptr, t);   // h0 slot t+1, hs slot t
    }

    f32x4 acc[2][4];
    #pragma unroll
    for (int mt = 0; mt < 2; ++mt)
      #pragma unroll
      for (int g = 0; g < 4; ++g) acc[mt][g] = (f32x4){0.f, 0.f, 0.f, 0.f};

    if (isL0) {
      int tok0 = (t == 0) ? EOS_ : targ[b0 * T_ + t - 1];
      int tok1 = (t == 0) ? EOS_ : targ[b1 * T_ + t - 1];
      const __hip_bfloat16* x0 = embB + (size_t)tok0 * E_;
      const __hip_bfloat16* x1 = embB + (size_t)tok1 * E_;
      const __hip_bfloat16* hh0 = h0hi + (size_t)t * BH_ + b0 * H_;
      const __hip_bfloat16* hh1 = h0hi + (size_t)t * BH_ + b1 * H_;
      const __hip_bfloat16* hr0 = h0res + (size_t)t * BH_ + b0 * H_;
      const __hip_bfloat16* hr1 = h0res + (size_t)t * BH_ + b1 * H_;
      #pragma unroll
      for (int ks = 0; ks < 8; ++ks) {
        const int ko = ks * 32 + klo * 8;
        bf16x8 ax0 = *(const bf16x8*)(x0 + ko);
        bf16x8 ax1 = *(const bf16x8*)(x1 + ko);
        bf16x8 ahh0 = *(const bf16x8*)(hh0 + ko);
        bf16x8 ahh1 = *(const bf16x8*)(hh1 + ko);
        bf16x8 ahr0 = *(const bf16x8*)(hr0 + ko);
        bf16x8 ahr1 = *(const bf16x8*)(hr1 + ko);
        #pragma unroll
        for (int g = 0; g < 4; ++g) {
          acc[0][g] = mfma16(ax0, bw1[g][ks], acc[0][g]);
          acc[1][g] = mfma16(ax1, bw1[g][ks], acc[1][g]);
          acc[0][g] = mfma16(ahh0, bw2[g][ks], acc[0][g]);
          acc[1][g] = mfma16(ahh1, bw2[g][ks], acc[1][g]);
          acc[0][g] = mfma16(ahr0, bw2[g][ks], acc[0][g]);
          acc[1][g] = mfma16(ahr1, bw2[g][ks], acc[1][g]);
        }
      }
    } else {
      const __hip_bfloat16* xh0 = h0hi + (size_t)(t + 1) * BH_ + b0 * H_;
      const __hip_bfloat16* xh1 = h0hi + (size_t)(t + 1) * BH_ + b1 * H_;
      const __hip_bfloat16* xr0 = h0res + (size_t)(t + 1) * BH_ + b0 * H_;
      const __hip_bfloat16* xr1 = h0res + (size_t)(t + 1) * BH_ + b1 * H_;
      const __hip_bfloat16* hh0 = hshi + (size_t)t * BH_ + b0 * H_;
      const __hip_bfloat16* hh1 = hshi + (size_t)t * BH_ + b1 * H_;
      const __hip_bfloat16* hr0 = hsres + (size_t)t * BH_ + b0 * H_;
      const __hip_bfloat16* hr1 = hsres + (size_t)t * BH_ + b1 * H_;
      #pragma unroll
      for (int ks = 0; ks < 8; ++ks) {
        const int ko = ks * 32 + klo * 8;
        bf16x8 axh0 = *(const bf16x8*)(xh0 + ko);
        bf16x8 axh1 = *(const bf16x8*)(xh1 + ko);
        bf16x8 axr0 = *(const bf16x8*)(xr0 + ko);
        bf16x8 axr1 = *(const bf16x8*)(xr1 + ko);
        bf16x8 ahh0 = *(const bf16x8*)(hh0 + ko);
        bf16x8 ahh1 = *(const bf16x8*)(hh1 + ko);
        bf16x8 ahr0 = *(const bf16x8*)(hr0 + ko);
        bf16x8 ahr1 = *(const bf16x8*)(hr1 + ko);
        #pragma unroll
        for (int g = 0; g < 4; ++g) {
          acc[0][g] = mfma16(axh0, bw1[g][ks], acc[0][g]);
          acc[1][g] = mfma16(axh1, bw1[g][ks], acc[1][g]);
          acc[0][g] = mfma16(axr0, bw1[g][ks], acc[0][g]);
          acc[1][g] = mfma16(axr1, bw1[g][ks], acc[1][g]);
          acc[0][g] = mfma16(ahh0, bw2[g][ks], acc[0][g]);
          acc[1][g] = mfma16(ahh1, bw2[g][ks], acc[1][g]);
          acc[0][g] = mfma16(ahr0, bw2[g][ks], acc[0][g]);
          acc[1][g] = mfma16(ahr1, bw2[g][ks], acc[1][g]);
        }
      }
    }

    // epilogue: gates -> h, write slot t+1 (hi/res), c stays in regs
    __hip_bfloat16* whi = (isL0 ? h0hi : hshi) + (size_t)(t + 1) * BH_;
    __hip_bfloat16* wre = (isL0 ? h0res : hsres) + (size_t)(t + 1) * BH_;
    #pragma unroll
    for (int mt = 0; mt < 2; ++mt) {
      #pragma unroll
      for (int r = 0; r < 4; ++r) {
        float iv = sigf(acc[mt][0][r] + bias[0]);
        float fv = sigf(acc[mt][1][r] + bias[1]);
        float gv = tanh_fast(acc[mt][2][r] + bias[2]);
        float ov = sigf(acc[mt][3][r] + bias[3]);
        float c = fv * cst[mt][r] + iv * gv;
        cst[mt][r] = c;
        float h = ov * tanh_fast(c);
        __hip_bfloat16 hi = __float2bfloat16(h);
        __hip_bfloat16 re = __float2bfloat16(h - __bfloat162float(hi));
        int brow = mbase + mt * 16 + klo * 4 + r;
        whi[(size_t)brow * H_ + hcol] = hi;
        wre[(size_t)brow * H_ + hcol] = re;
      }
    }
    signal_flag((isL0 ? flag0 : flag1) + chunk * 32);
  }
}

// ---------------------------------------------------------------------------
// logits = hs @ WoutBf^T + b_out.  128x128 tile, BK=32, double-buffered
// global_load_lds staging, LDS frag reads. Output [B][T][V] f32. (unchanged)
// ---------------------------------------------------------------------------
__global__ __launch_bounds__(256) void gemm_out(
    const __hip_bfloat16* __restrict__ hs,
    const __hip_bfloat16* __restrict__ Wb, const float* __restrict__ bout,
    float* __restrict__ out) {
  __shared__ __hip_bfloat16 ldsA[2][128 * 32];
  __shared__ __hip_bfloat16 ldsB[2][128 * 32];

  const int tid = threadIdx.x;
  const int lane = tid & 63;
  const int wave = tid >> 6;
  const int wr = wave >> 1, wc = wave & 1;
  const int m0 = blockIdx.x * 128;
  const int n0 = blockIdx.y * 128;
  const int row_in = lane & 15;
  const int kgrp = lane >> 4;

  auto stage = [&](int kb, int buf) {
    #pragma unroll
    for (int p = 0; p < 2; ++p) {
      int slot = p * 256 + wave * 64 + lane;
      int row = slot >> 2;
      int k16 = slot & 3;
      const __hip_bfloat16* srcA = hs + (size_t)(m0 + row) * H_ + kb * 32 + k16 * 8;
      int rn = n0 + row; if (rn >= V_) rn = V_ - 1;
      const __hip_bfloat16* srcB = Wb + (size_t)rn * H_ + kb * 32 + k16 * 8;
      __hip_bfloat16* dstA = &ldsA[buf][0] + (p * 2048 + wave * 512);
      __hip_bfloat16* dstB = &ldsB[buf][0] + (p * 2048 + wave * 512);
      __builtin_amdgcn_global_load_lds(
          (const __attribute__((address_space(1))) unsigned int*)srcA,
          (__attribute__((address_space(3))) unsigned int*)dstA, 16, 0, 0);
      __builtin_amdgcn_global_load_lds(
          (const __attribute__((address_space(1))) unsigned int*)srcB,
          (__attribute__((address_space(3))) unsigned int*)dstB, 16, 0, 0);
    }
  };

  f32x4 acc[4][4];
  #pragma unroll
  for (int i = 0; i < 4; ++i)
    #pragma unroll
    for (int j = 0; j < 4; ++j) acc[i][j] = (f32x4){0.f, 0.f, 0.f, 0.f};

  stage(0, 0);
  __syncthreads();

  int buf = 0;
  for (int kb = 0; kb < 8; ++kb) {
    if (kb < 7) stage(kb + 1, buf ^ 1);
    bf16x8 a[4], b[4];
    #pragma unroll
    for (int mi = 0; mi < 4; ++mi) {
      int row = wr * 64 + mi * 16 + row_in;
      a[mi] = *(const bf16x8*)(&ldsA[buf][0] + row * 32 + kgrp * 8);
    }
    #pragma unroll
    for (int ni = 0; ni < 4; ++ni) {
      int row = wc * 64 + ni * 16 + row_in;
      b[ni] = *(const bf16x8*)(&ldsB[buf][0] + row * 32 + kgrp * 8);
    }
    #pragma unroll
    for (int mi = 0; mi < 4; ++mi)
      #pragma unroll
      for (int ni = 0; ni < 4; ++ni)
        acc[mi][ni] = mfma16(a[mi], b[ni], acc[mi][ni]);
    __syncthreads();
    buf ^= 1;
  }

  #pragma unroll
  for (int ni = 0; ni < 4; ++ni) {
    int v = n0 + wc * 64 + ni * 16 + row_in;
    if (v >= V_) continue;
    float bias = bout[v];
    #pragma unroll
    for (int mi = 0; mi < 4; ++mi) {
      #pragma unroll
      for (int r = 0; r < 4; ++r) {
        int m = m0 + wr * 64 + mi * 16 + kgrp * 4 + r;
        int tt = m >> 7;
        int bb_ = m & 127;
        out[((size_t)bb_ * T_ + tt) * V_ + v] = acc[mi][ni][r] + bias;
      }
    }
  }
}

// ---------------------------------------------------------------------------
extern "C" void kernel_launch(void* const* d_in, const int* in_sizes, int n_in,
                              void* d_out, int out_size, void* d_ws, size_t ws_size,
                              hipStream_t stream) {
  const float* z     = (const float*)d_in[0];
  const int*   targ  = (const int*)d_in[1];
  const float* emb   = (const float*)d_in[2];
  const float* W_ih0 = (const float*)d_in[3];
  const float* W_hh0 = (const float*)d_in[4];
  const float* b_ih0 = (const float*)d_in[5];
  const float* b_hh0 = (const float*)d_in[6];
  const float* W_ih1 = (const float*)d_in[7];
  const float* W_hh1 = (const float*)d_in[8];
  const float* b_ih1 = (const float*)d_in[9];
  const float* b_hh1 = (const float*)d_in[10];
  const float* W_out = (const float*)d_in[11];
  const float* b_out = (const float*)d_in[12];
  const float* W_lat = (const float*)d_in[13];
  const float* b_lat = (const float*)d_in[14];
  float* out = (float*)d_out;

  char* ws = (char*)d_ws;
  __hip_bfloat16* h0hi  = (__hip_bfloat16*)(ws);              // 65*BH*2 = 4,259,840
  __hip_bfloat16* h0res = (__hip_bfloat16*)(ws + 4259840);
  __hip_bfloat16* hshi  = (__hip_bfloat16*)(ws + 8519680);
  __hip_bfloat16* hsres = (__hip_bfloat16*)(ws + 12779520);
  __hip_bfloat16* embB  = (__hip_bfloat16*)(ws + 17039360);   // 15,627,264
  __hip_bfloat16* Wih0B = (__hip_bfloat16*)(ws + 32666624);   // 524,288
  __hip_bfloat16* Whh0B = (__hip_bfloat16*)(ws + 33190912);
  __hip_bfloat16* Wih1B = (__hip_bfloat16*)(ws + 33715200);
  __hip_bfloat16* Whh1B = (__hip_bfloat16*)(ws + 34239488);
  __hip_bfloat16* WoutB = (__hip_bfloat16*)(ws + 34763776);   // 15,627,264
  int* flag0 = (int*)(ws + 50391040);                         // 16 x 128B
  int* flag1 = flag0 + 512;                                   // 16 x 128B
  int* ticket = flag0 + 1024;                                 // 1 int

  reset_cnt<<<5, 256, 0, stream>>>(flag0);
  conv_bf16<<<3816, 256, 0, stream>>>(emb, embB, V_ * E_);
  conv_bf16<<<128, 256, 0, stream>>>(W_ih0, Wih0B, 1024 * 256);
  conv_bf16<<<128, 256, 0, stream>>>(W_hh0, Whh0B, 1024 * 256);
  conv_bf16<<<128, 256, 0, stream>>>(W_ih1, Wih1B, 1024 * 256);
  conv_bf16<<<128, 256, 0, stream>>>(W_hh1, Whh1B, 1024 * 256);
  conv_bf16<<<3816, 256, 0, stream>>>(W_out, WoutB, V_ * H_);
  init_kernel<<<128, 256, 0, stream>>>(z, W_lat, b_lat, h0hi, h0res, hshi, hsres);

  lstm_persist<<<512, 256, 0, stream>>>(
      targ, embB,
      Wih0B, Whh0B, b_ih0, b_hh0,
      Wih1B, Whh1B, b_ih1, b_hh1,
      h0hi, h0res, hshi, hsres, flag0, flag1, ticket);

  {
    dim3 g(64, 239);
    gemm_out<<<g, 256, 0, stream>>>(hshi + BH_, WoutB, b_out, out);
  }
}

// Round 13
// 1066.914 us; speedup vs baseline: 1.4735x; 1.4735x over previous
//
#include <hip/hip_runtime.h>
#include <hip/hip_bf16.h>

#define B_ 128
#define T_ 64
#define H_ 256
#define E_ 256
#define L_ 512
#define V_ 30522
#define EOS_ 2
#define BH_ (B_ * H_)

typedef __attribute__((ext_vector_type(8))) short bf16x8;
typedef __attribute__((ext_vector_type(4))) float f32x4;

__device__ __forceinline__ float4 ld4(const float* p) { return *(const float4*)p; }
__device__ __forceinline__ float dot4(float4 a, float4 b) {
  return a.x * b.x + a.y * b.y + a.z * b.z + a.w * b.w;
}
__device__ __forceinline__ float sigf(float x) {
  return __builtin_amdgcn_rcpf(1.f + __expf(-x));
}
__device__ __forceinline__ float tanh_fast(float x) {
  float e = __expf(2.f * x);
  return 1.f - 2.f * __builtin_amdgcn_rcpf(e + 1.f);
}
__device__ __forceinline__ f32x4 mfma16(bf16x8 a, bf16x8 b, f32x4 c) {
  return __builtin_amdgcn_mfma_f32_16x16x32_bf16(a, b, c, 0, 0, 0);
}

// ---------------------------------------------------------------------------
// generic f32 -> bf16 convert (total % 8 == 0)
// ---------------------------------------------------------------------------
__global__ __launch_bounds__(256) void conv_bf16(
    const float* __restrict__ src, __hip_bfloat16* __restrict__ dst, int total) {
  int i = (blockIdx.x * 256 + threadIdx.x) * 8;
  if (i + 8 <= total) {
    float4 lo = ld4(src + i), hi = ld4(src + i + 4);
    union { bf16x8 v8; __hip_bfloat16 e[8]; } u;
    u.e[0] = __float2bfloat16(lo.x); u.e[1] = __float2bfloat16(lo.y);
    u.e[2] = __float2bfloat16(lo.z); u.e[3] = __float2bfloat16(lo.w);
    u.e[4] = __float2bfloat16(hi.x); u.e[5] = __float2bfloat16(hi.y);
    u.e[6] = __float2bfloat16(hi.z); u.e[7] = __float2bfloat16(hi.w);
    *(bf16x8*)(dst + i) = u.v8;
  }
}

// zero flags (8 gangs x 1024 ints) + tickets (8 x 32 ints) = 8448 ints
__global__ __launch_bounds__(256) void reset_cnt(int* __restrict__ c) {
  int i = blockIdx.x * 256 + threadIdx.x;
  if (i < 8448) c[i] = 0;
}

// ---------------------------------------------------------------------------
// init: h_init = z @ W_lat^T + b_lat -> slot 0 of h0 & hs (hi+res)
// ---------------------------------------------------------------------------
__global__ __launch_bounds__(256) void init_kernel(
    const float* __restrict__ z, const float* __restrict__ W_lat,
    const float* __restrict__ b_lat,
    __hip_bfloat16* __restrict__ h0hi, __hip_bfloat16* __restrict__ h0res,
    __hip_bfloat16* __restrict__ hshi, __hip_bfloat16* __restrict__ hsres) {
  int b = blockIdx.x;
  int h = threadIdx.x;
  const float* zr = z + (size_t)b * L_;
  const float* wr = W_lat + (size_t)h * L_;
  float acc = b_lat[h];
  #pragma unroll 4
  for (int l = 0; l < L_; l += 4) acc += dot4(ld4(zr + l), ld4(wr + l));
  __hip_bfloat16 hi = __float2bfloat16(acc);
  __hip_bfloat16 re = __float2bfloat16(acc - __bfloat162float(hi));
  int idx = b * H_ + h;
  h0hi[idx] = hi; h0res[idx] = re;
  hshi[idx] = hi; hsres[idx] = re;
}

// ---------------------------------------------------------------------------
// Persistent recurrence: 8 INDEPENDENT per-XCD gangs, 16 batch rows each.
// Gang = 32 blocks on one XCD: roles 0-15 layer0, 16-31 layer1; role r owns
// h-cols [chunk*16, chunk*16+16). Wave w of a block computes gate w only ->
// weights per wave = 16 bf16x8 frags = 64 VGPR -> truly register-resident
// (R12's 256-VGPR ambition was silently rematerialized: VGPR_Count=192).
// Gate combine via 4.3KB padded LDS. c-state per epilogue-thread register.
// Sync: plain atomicAdd for signal AND poll (RMWs never read stale L1 --
// R10 lesson; same path both sides -> self-consistent visibility). All
// producer/consumer pairs share the XCD's L2; stores drained by the
// vmcnt(0) in __syncthreads before signaling. Spin caps -> loud failure.
// ---------------------------------------------------------------------------
__global__ __launch_bounds__(256, 1) void lstm_persist(
    const int* __restrict__ targ, const __hip_bfloat16* __restrict__ embB,
    const __hip_bfloat16* __restrict__ Wih0B, const __hip_bfloat16* __restrict__ Whh0B,
    const float* __restrict__ b_ih0, const float* __restrict__ b_hh0,
    const __hip_bfloat16* __restrict__ Wih1B, const __hip_bfloat16* __restrict__ Whh1B,
    const float* __restrict__ b_ih1, const float* __restrict__ b_hh1,
    __hip_bfloat16* __restrict__ h0hi, __hip_bfloat16* __restrict__ h0res,
    __hip_bfloat16* __restrict__ hshi, __hip_bfloat16* __restrict__ hsres,
    int* __restrict__ flags, int* __restrict__ tickets) {
  __shared__ int role_sh;
  __shared__ int gang_sh;
  if (threadIdx.x == 0) {
    unsigned xcd;
    asm volatile("s_getreg_b32 %0, hwreg(HW_REG_XCC_ID)" : "=s"(xcd));
    xcd &= 7u;
    role_sh = __hip_atomic_fetch_add(tickets + xcd * 32, 1, __ATOMIC_RELAXED,
                                     __HIP_MEMORY_SCOPE_AGENT);
    gang_sh = (int)xcd;
  }
  __syncthreads();
  const int role = role_sh;
  if (role >= 32) return;
  const int gang = gang_sh;
  const bool isL0 = role < 16;
  const int chunk = role & 15;

  int* flag0 = flags + gang * 1024;   // 16 producers x 32-int (128B) spacing
  int* flag1 = flag0 + 512;

  const int tid = threadIdx.x;
  const int lane = tid & 63;
  const int wave = tid >> 6;        // gate index g (i,f,g,o = 0..3)
  const int arow = lane & 15;       // batch-row (A) / h-col (B,C) selector
  const int klo = lane >> 4;
  const int hcol = chunk * 16 + arow;
  const int brow0 = gang * 16;      // gang's first batch row
  const int myrow = brow0 + arow;

  // --- weights: one gate per wave -> 16 frags, stays in VGPRs ---
  const __hip_bfloat16* W1 = isL0 ? Wih0B : Wih1B;
  const __hip_bfloat16* W2 = isL0 ? Whh0B : Whh1B;
  bf16x8 bw1[8], bw2[8];
  {
    const size_t wrow = (size_t)(wave * 256 + hcol) * 256;
    #pragma unroll
    for (int ks = 0; ks < 8; ++ks) {
      bw1[ks] = *(const bf16x8*)(W1 + wrow + ks * 32 + klo * 8);
      bw2[ks] = *(const bf16x8*)(W2 + wrow + ks * 32 + klo * 8);
    }
  }

  // --- epilogue thread mapping: tid -> (erow, ecol), c in register ---
  const int erow = tid >> 4;    // batch-row local 0..15
  const int ecol = tid & 15;    // h-col local
  const float* bi = isL0 ? b_ih0 : b_ih1;
  const float* bh = isL0 ? b_hh0 : b_hh1;
  const int ehcol = chunk * 16 + ecol;
  const float bias_i = bi[ehcol] + bh[ehcol];
  const float bias_f = bi[256 + ehcol] + bh[256 + ehcol];
  const float bias_g = bi[512 + ehcol] + bh[512 + ehcol];
  const float bias_o = bi[768 + ehcol] + bh[768 + ehcol];
  float c_state = 0.f;

  __shared__ float glds[4][16][17];

  for (int t = 0; t < T_; ++t) {
    // ---- wait: lanes 0-15 poll flag0, 16-31 poll flag1 ----
    {
      const int need0 = isL0 ? t : t + 1;
      const int need1 = isL0 ? 0 : t;
      if (tid < 64) {
        int* p = nullptr; int need = 0;
        if (lane < 16) { p = flag0 + lane * 32; need = need0; }
        else if (lane < 32) { p = flag1 + (lane - 16) * 32; need = need1; }
        int it = 0;
        for (;;) {
          bool ok = true;
          if (p && need > 0) ok = (atomicAdd(p, 0) >= need);
          if (__all(ok)) break;
          if (++it >= (1 << 14)) break;   // loud failure, not a hang
          __builtin_amdgcn_s_sleep(1);
        }
      }
      __syncthreads();
    }

    // ---- gate GEMM: this wave's gate, 16 rows x 16 cols, K=256 ----
    f32x4 acc0 = (f32x4){0.f, 0.f, 0.f, 0.f};
    f32x4 acc1 = (f32x4){0.f, 0.f, 0.f, 0.f};
    if (isL0) {
      int tok = (t == 0) ? EOS_ : targ[myrow * T_ + t - 1];
      const __hip_bfloat16* xp = embB + (size_t)tok * E_;
      const __hip_bfloat16* hhp = h0hi + (size_t)t * BH_ + myrow * H_;
      const __hip_bfloat16* hrp = h0res + (size_t)t * BH_ + myrow * H_;
      #pragma unroll
      for (int ks = 0; ks < 8; ++ks) {
        const int ko = ks * 32 + klo * 8;
        bf16x8 ax = *(const bf16x8*)(xp + ko);
        bf16x8 ahh = *(const bf16x8*)(hhp + ko);
        bf16x8 ahr = *(const bf16x8*)(hrp + ko);
        if (ks & 1) {
          acc1 = mfma16(ax, bw1[ks], acc1);
          acc1 = mfma16(ahh, bw2[ks], acc1);
          acc1 = mfma16(ahr, bw2[ks], acc1);
        } else {
          acc0 = mfma16(ax, bw1[ks], acc0);
          acc0 = mfma16(ahh, bw2[ks], acc0);
          acc0 = mfma16(ahr, bw2[ks], acc0);
        }
      }
    } else {
      const __hip_bfloat16* xhp = h0hi + (size_t)(t + 1) * BH_ + myrow * H_;
      const __hip_bfloat16* xrp = h0res + (size_t)(t + 1) * BH_ + myrow * H_;
      const __hip_bfloat16* hhp = hshi + (size_t)t * BH_ + myrow * H_;
      const __hip_bfloat16* hrp = hsres + (size_t)t * BH_ + myrow * H_;
      #pragma unroll
      for (int ks = 0; ks < 8; ++ks) {
        const int ko = ks * 32 + klo * 8;
        bf16x8 axh = *(const bf16x8*)(xhp + ko);
        bf16x8 axr = *(const bf16x8*)(xrp + ko);
        bf16x8 ahh = *(const bf16x8*)(hhp + ko);
        bf16x8 ahr = *(const bf16x8*)(hrp + ko);
        if (ks & 1) {
          acc1 = mfma16(axh, bw1[ks], acc1);
          acc1 = mfma16(axr, bw1[ks], acc1);
          acc1 = mfma16(ahh, bw2[ks], acc1);
          acc1 = mfma16(ahr, bw2[ks], acc1);
        } else {
          acc0 = mfma16(axh, bw1[ks], acc0);
          acc0 = mfma16(axr, bw1[ks], acc0);
          acc0 = mfma16(ahh, bw2[ks], acc0);
          acc0 = mfma16(ahr, bw2[ks], acc0);
        }
      }
    }
    // C layout: col = lane&15 (h-col), row = klo*4 + r (batch row)
    #pragma unroll
    for (int r = 0; r < 4; ++r)
      glds[wave][klo * 4 + r][arow] = acc0[r] + acc1[r];
    __syncthreads();

    // ---- cell epilogue: one thread per (row, col); c stays in register ----
    {
      float gi = glds[0][erow][ecol] + bias_i;
      float gf = glds[1][erow][ecol] + bias_f;
      float gg = glds[2][erow][ecol] + bias_g;
      float go = glds[3][erow][ecol] + bias_o;
      float iv = sigf(gi), fv = sigf(gf), gv = tanh_fast(gg), ov = sigf(go);
      c_state = fv * c_state + iv * gv;
      float h = ov * tanh_fast(c_state);
      __hip_bfloat16 hi = __float2bfloat16(h);
      __hip_bfloat16 re = __float2bfloat16(h - __bfloat162float(hi));
      size_t off = (size_t)(t + 1) * BH_ + (size_t)(brow0 + erow) * H_ + ehcol;
      (isL0 ? h0hi : hshi)[off] = hi;
      (isL0 ? h0res : hsres)[off] = re;
    }

    // ---- signal: stores drained by barrier, then RMW ----
    __syncthreads();
    if (tid == 0) atomicAdd((isL0 ? flag0 : flag1) + chunk * 32, 1);
  }
}

// ---------------------------------------------------------------------------
// logits = hs @ WoutBf^T + b_out.  128x128 tile, BK=32, double-buffered
// global_load_lds staging, LDS frag reads. Output [B][T][V] f32. (unchanged)
// ---------------------------------------------------------------------------
__global__ __launch_bounds__(256) void gemm_out(
    const __hip_bfloat16* __restrict__ hs,
    const __hip_bfloat16* __restrict__ Wb, const float* __restrict__ bout,
    float* __restrict__ out) {
  __shared__ __hip_bfloat16 ldsA[2][128 * 32];
  __shared__ __hip_bfloat16 ldsB[2][128 * 32];

  const int tid = threadIdx.x;
  const int lane = tid & 63;
  const int wave = tid >> 6;
  const int wr = wave >> 1, wc = wave & 1;
  const int m0 = blockIdx.x * 128;
  const int n0 = blockIdx.y * 128;
  const int row_in = lane & 15;
  const int kgrp = lane >> 4;

  auto stage = [&](int kb, int buf) {
    #pragma unroll
    for (int p = 0; p < 2; ++p) {
      int slot = p * 256 + wave * 64 + lane;
      int row = slot >> 2;
      int k16 = slot & 3;
      const __hip_bfloat16* srcA = hs + (size_t)(m0 + row) * H_ + kb * 32 + k16 * 8;
      int rn = n0 + row; if (rn >= V_) rn = V_ - 1;
      const __hip_bfloat16* srcB = Wb + (size_t)rn * H_ + kb * 32 + k16 * 8;
      __hip_bfloat16* dstA = &ldsA[buf][0] + (p * 2048 + wave * 512);
      __hip_bfloat16* dstB = &ldsB[buf][0] + (p * 2048 + wave * 512);
      __builtin_amdgcn_global_load_lds(
          (const __attribute__((address_space(1))) unsigned int*)srcA,
          (__attribute__((address_space(3))) unsigned int*)dstA, 16, 0, 0);
      __builtin_amdgcn_global_load_lds(
          (const __attribute__((address_space(1))) unsigned int*)srcB,
          (__attribute__((address_space(3))) unsigned int*)dstB, 16, 0, 0);
    }
  };

  f32x4 acc[4][4];
  #pragma unroll
  for (int i = 0; i < 4; ++i)
    #pragma unroll
    for (int j = 0; j < 4; ++j) acc[i][j] = (f32x4){0.f, 0.f, 0.f, 0.f};

  stage(0, 0);
  __syncthreads();

  int buf = 0;
  for (int kb = 0; kb < 8; ++kb) {
    if (kb < 7) stage(kb + 1, buf ^ 1);
    bf16x8 a[4], b[4];
    #pragma unroll
    for (int mi = 0; mi < 4; ++mi) {
      int row = wr * 64 + mi * 16 + row_in;
      a[mi] = *(const bf16x8*)(&ldsA[buf][0] + row * 32 + kgrp * 8);
    }
    #pragma unroll
    for (int ni = 0; ni < 4; ++ni) {
      int row = wc * 64 + ni * 16 + row_in;
      b[ni] = *(const bf16x8*)(&ldsB[buf][0] + row * 32 + kgrp * 8);
    }
    #pragma unroll
    for (int mi = 0; mi < 4; ++mi)
      #pragma unroll
      for (int ni = 0; ni < 4; ++ni)
        acc[mi][ni] = mfma16(a[mi], b[ni], acc[mi][ni]);
    __syncthreads();
    buf ^= 1;
  }

  #pragma unroll
  for (int ni = 0; ni < 4; ++ni) {
    int v = n0 + wc * 64 + ni * 16 + row_in;
    if (v >= V_) continue;
    float bias = bout[v];
    #pragma unroll
    for (int mi = 0; mi < 4; ++mi) {
      #pragma unroll
      for (int r = 0; r < 4; ++r) {
        int m = m0 + wr * 64 + mi * 16 + kgrp * 4 + r;
        int tt = m >> 7;
        int bb_ = m & 127;
        out[((size_t)bb_ * T_ + tt) * V_ + v] = acc[mi][ni][r] + bias;
      }
    }
  }
}

// ---------------------------------------------------------------------------
extern "C" void kernel_launch(void* const* d_in, const int* in_sizes, int n_in,
                              void* d_out, int out_size, void* d_ws, size_t ws_size,
                              hipStream_t stream) {
  const float* z     = (const float*)d_in[0];
  const int*   targ  = (const int*)d_in[1];
  const float* emb   = (const float*)d_in[2];
  const float* W_ih0 = (const float*)d_in[3];
  const float* W_hh0 = (const float*)d_in[4];
  const float* b_ih0 = (const float*)d_in[5];
  const float* b_hh0 = (const float*)d_in[6];
  const float* W_ih1 = (const float*)d_in[7];
  const float* W_hh1 = (const float*)d_in[8];
  const float* b_ih1 = (const float*)d_in[9];
  const float* b_hh1 = (const float*)d_in[10];
  const float* W_out = (const float*)d_in[11];
  const float* b_out = (const float*)d_in[12];
  const float* W_lat = (const float*)d_in[13];
  const float* b_lat = (const float*)d_in[14];
  float* out = (float*)d_out;

  char* ws = (char*)d_ws;
  __hip_bfloat16* h0hi  = (__hip_bfloat16*)(ws);              // 65*BH*2 = 4,259,840
  __hip_bfloat16* h0res = (__hip_bfloat16*)(ws + 4259840);
  __hip_bfloat16* hshi  = (__hip_bfloat16*)(ws + 8519680);
  __hip_bfloat16* hsres = (__hip_bfloat16*)(ws + 12779520);
  __hip_bfloat16* embB  = (__hip_bfloat16*)(ws + 17039360);   // 15,627,264
  __hip_bfloat16* Wih0B = (__hip_bfloat16*)(ws + 32666624);   // 524,288
  __hip_bfloat16* Whh0B = (__hip_bfloat16*)(ws + 33190912);
  __hip_bfloat16* Wih1B = (__hip_bfloat16*)(ws + 33715200);
  __hip_bfloat16* Whh1B = (__hip_bfloat16*)(ws + 34239488);
  __hip_bfloat16* WoutB = (__hip_bfloat16*)(ws + 34763776);   // 15,627,264
  int* flags = (int*)(ws + 50391040);                         // 8 x 1024 ints
  int* tickets = flags + 8192;                                // 8 x 32 ints

  reset_cnt<<<33, 256, 0, stream>>>(flags);
  conv_bf16<<<3816, 256, 0, stream>>>(emb, embB, V_ * E_);
  conv_bf16<<<128, 256, 0, stream>>>(W_ih0, Wih0B, 1024 * 256);
  conv_bf16<<<128, 256, 0, stream>>>(W_hh0, Whh0B, 1024 * 256);
  conv_bf16<<<128, 256, 0, stream>>>(W_ih1, Wih1B, 1024 * 256);
  conv_bf16<<<128, 256, 0, stream>>>(W_hh1, Whh1B, 1024 * 256);
  conv_bf16<<<3816, 256, 0, stream>>>(W_out, WoutB, V_ * H_);
  init_kernel<<<128, 256, 0, stream>>>(z, W_lat, b_lat, h0hi, h0res, hshi, hsres);

  lstm_persist<<<512, 256, 0, stream>>>(
      targ, embB,
      Wih0B, Whh0B, b_ih0, b_hh0,
      Wih1B, Whh1B, b_ih1, b_hh1,
      h0hi, h0res, hshi, hsres, flags, tickets);

  {
    dim3 g(64, 239);
    gemm_out<<<g, 256, 0, stream>>>(hshi + BH_, WoutB, b_out, out);
  }
}